// Round 1
// baseline (1463.390 us; speedup 1.0000x reference)
//
#include <hip/hip_runtime.h>
#include <math.h>

#define NN 100000
#define NE 1600000

// ws layout in floats
#define OFS_CNT   0
#define OFS_AGG1  (NN)
#define OFS_AGG2  (65 * NN)
#define OFS_H1    (193 * NN)
#define OFS_INV   (321 * NN)
#define OFS_STATS (322 * NN)
#define OFS_PART  (322 * NN + 256)
#define PART_BLOCKS 512

// ---------------- scatter layer 1: agg1[dst] += x[src], cnt[dst] += 1 ----------------
__global__ void k_scatter1(const float* __restrict__ x, const int* __restrict__ ei,
                           float* __restrict__ agg1, float* __restrict__ cnt) {
    unsigned gid = blockIdx.x * 256u + threadIdx.x;
    unsigned e = gid >> 6, f = gid & 63u;
    if (e < NE) {
        int s = ei[e], d = ei[NE + e];
        atomicAdd(&agg1[d * 64 + f], x[s * 64 + f]);
        if (f == 0) atomicAdd(&cnt[d], 1.0f);
    }
}

__global__ void k_invcnt(const float* __restrict__ cnt, float* __restrict__ inv) {
    int i = blockIdx.x * 256 + threadIdx.x;
    if (i < NN) inv[i] = 1.0f / fmaxf(cnt[i], 1.0f);
}

// ---------------- layer 1: out = agg*inv @ w1l + b1l + x @ w1r ; L2norm ; relu ; BN col stats ----------------
__global__ __launch_bounds__(256) void k_gemm1(
    const float* __restrict__ agg1, const float* __restrict__ x,
    const float* __restrict__ inv,
    const float* __restrict__ w1l, const float* __restrict__ b1l,
    const float* __restrict__ w1r,
    float* __restrict__ h1, float* __restrict__ part) {
    __shared__ float wt[64 * 128];   // 32 KB weight tile
    __shared__ float inA[16 * 64];   // scaled agg rows
    __shared__ float inB[16 * 64];   // x rows
    __shared__ float cs[128];
    __shared__ float cq[128];
    const int t = threadIdx.x;
    const int jq = t & 31;   // 4 cols: jq*4..jq*4+3
    const int ngq = t >> 5;  // 2 nodes: ngq*2, ngq*2+1
    if (t < 128) { cs[t] = 0.f; cq[t] = 0.f; }
    float ls0 = 0, ls1 = 0, ls2 = 0, ls3 = 0;
    float lq0 = 0, lq1 = 0, lq2 = 0, lq3 = 0;
    const float4* w1l4 = (const float4*)w1l;
    const float4* w1r4 = (const float4*)w1r;
    float4* wt4 = (float4*)wt;
    const float4 bv = ((const float4*)b1l)[jq];

    for (int g = blockIdx.x; g < NN / 16; g += gridDim.x) {
        const int base = g * 16;
        {   // stage 16 nodes x 64 feats for both inputs (1 float4 per thread each)
            int node = t >> 4, kq = t & 15;
            float ic = inv[base + node];
            float4 a = ((const float4*)agg1)[(base + node) * 16 + kq];
            a.x *= ic; a.y *= ic; a.z *= ic; a.w *= ic;
            ((float4*)inA)[t] = a;
            ((float4*)inB)[t] = ((const float4*)x)[(base + node) * 16 + kq];
        }
#pragma unroll
        for (int i = 0; i < 8; i++) wt4[t + 256 * i] = w1l4[t + 256 * i];
        __syncthreads();

        float4 acc0 = bv, acc1 = bv;
        const int r0 = (ngq * 2) * 64, r1 = (ngq * 2 + 1) * 64;
#pragma unroll
        for (int k = 0; k < 64; k++) {
            float4 w4 = wt4[k * 32 + jq];
            float a0 = inA[r0 + k], a1 = inA[r1 + k];
            acc0.x += a0 * w4.x; acc0.y += a0 * w4.y; acc0.z += a0 * w4.z; acc0.w += a0 * w4.w;
            acc1.x += a1 * w4.x; acc1.y += a1 * w4.y; acc1.z += a1 * w4.z; acc1.w += a1 * w4.w;
        }
        __syncthreads();
#pragma unroll
        for (int i = 0; i < 8; i++) wt4[t + 256 * i] = w1r4[t + 256 * i];
        __syncthreads();
#pragma unroll
        for (int k = 0; k < 64; k++) {
            float4 w4 = wt4[k * 32 + jq];
            float a0 = inB[r0 + k], a1 = inB[r1 + k];
            acc0.x += a0 * w4.x; acc0.y += a0 * w4.y; acc0.z += a0 * w4.z; acc0.w += a0 * w4.w;
            acc1.x += a1 * w4.x; acc1.y += a1 * w4.y; acc1.z += a1 * w4.z; acc1.w += a1 * w4.w;
        }
        // epilogue node 0
        {
            float ss = acc0.x * acc0.x + acc0.y * acc0.y + acc0.z * acc0.z + acc0.w * acc0.w;
            ss += __shfl_xor(ss, 1); ss += __shfl_xor(ss, 2); ss += __shfl_xor(ss, 4);
            ss += __shfl_xor(ss, 8); ss += __shfl_xor(ss, 16);
            float iv = 1.0f / fmaxf(sqrtf(ss), 1e-12f);
            float v0 = fmaxf(acc0.x * iv, 0.f), v1 = fmaxf(acc0.y * iv, 0.f);
            float v2 = fmaxf(acc0.z * iv, 0.f), v3 = fmaxf(acc0.w * iv, 0.f);
            float4 o; o.x = v0; o.y = v1; o.z = v2; o.w = v3;
            ((float4*)&h1[(base + ngq * 2) * 128])[jq] = o;
            ls0 += v0; ls1 += v1; ls2 += v2; ls3 += v3;
            lq0 += v0 * v0; lq1 += v1 * v1; lq2 += v2 * v2; lq3 += v3 * v3;
        }
        // epilogue node 1
        {
            float ss = acc1.x * acc1.x + acc1.y * acc1.y + acc1.z * acc1.z + acc1.w * acc1.w;
            ss += __shfl_xor(ss, 1); ss += __shfl_xor(ss, 2); ss += __shfl_xor(ss, 4);
            ss += __shfl_xor(ss, 8); ss += __shfl_xor(ss, 16);
            float iv = 1.0f / fmaxf(sqrtf(ss), 1e-12f);
            float v0 = fmaxf(acc1.x * iv, 0.f), v1 = fmaxf(acc1.y * iv, 0.f);
            float v2 = fmaxf(acc1.z * iv, 0.f), v3 = fmaxf(acc1.w * iv, 0.f);
            float4 o; o.x = v0; o.y = v1; o.z = v2; o.w = v3;
            ((float4*)&h1[(base + ngq * 2 + 1) * 128])[jq] = o;
            ls0 += v0; ls1 += v1; ls2 += v2; ls3 += v3;
            lq0 += v0 * v0; lq1 += v1 * v1; lq2 += v2 * v2; lq3 += v3 * v3;
        }
        __syncthreads();  // before next staging overwrites LDS
    }
    // flush per-block BN partial stats
    __syncthreads();
    atomicAdd(&cs[jq * 4 + 0], ls0); atomicAdd(&cs[jq * 4 + 1], ls1);
    atomicAdd(&cs[jq * 4 + 2], ls2); atomicAdd(&cs[jq * 4 + 3], ls3);
    atomicAdd(&cq[jq * 4 + 0], lq0); atomicAdd(&cq[jq * 4 + 1], lq1);
    atomicAdd(&cq[jq * 4 + 2], lq2); atomicAdd(&cq[jq * 4 + 3], lq3);
    __syncthreads();
    if (t < 128) {
        part[blockIdx.x * 256 + t] = cs[t];
        part[blockIdx.x * 256 + 128 + t] = cq[t];
    }
}

// ---------------- BN finalize: scale/shift from partials ----------------
__global__ void k_bnfin(const float* __restrict__ part, const float* __restrict__ gamma,
                        const float* __restrict__ beta, float* __restrict__ stats) {
    int t = threadIdx.x;  // 128
    float s = 0.f, q = 0.f;
    for (int b = 0; b < PART_BLOCKS; b++) {
        s += part[b * 256 + t];
        q += part[b * 256 + 128 + t];
    }
    float mean = s / (float)NN;
    float var = q / (float)NN - mean * mean;
    float sc = gamma[t] * rsqrtf(var + 1e-5f);
    stats[t] = sc;
    stats[128 + t] = beta[t] - mean * sc;
}

// ---------------- BN apply in place on h1 ----------------
__global__ void k_bnapply(float* __restrict__ h1, const float* __restrict__ stats) {
    int i = blockIdx.x * 256 + threadIdx.x;  // float4 index < NN*32
    if (i < NN * 32) {
        int jq = i & 31;
        float4 v = ((float4*)h1)[i];
        float4 sc = ((const float4*)stats)[jq];
        float4 sh = ((const float4*)stats)[32 + jq];
        v.x = v.x * sc.x + sh.x; v.y = v.y * sc.y + sh.y;
        v.z = v.z * sc.z + sh.z; v.w = v.w * sc.w + sh.w;
        ((float4*)h1)[i] = v;
    }
}

// ---------------- scatter layer 2: agg2[dst] += h1[src] ----------------
__global__ void k_scatter2(const float* __restrict__ h1, const int* __restrict__ ei,
                           float* __restrict__ agg2) {
    unsigned gid = blockIdx.x * 256u + threadIdx.x;
    unsigned e = gid >> 7, f = gid & 127u;
    if (e < NE) {
        int s = ei[e], d = ei[NE + e];
        atomicAdd(&agg2[d * 128 + f], h1[s * 128 + f]);
    }
}

// ---------------- layer 2 + L2norm + FC, fused ----------------
__global__ __launch_bounds__(256) void k_gemm2(
    const float* __restrict__ agg2, const float* __restrict__ h1,
    const float* __restrict__ inv,
    const float* __restrict__ w2l, const float* __restrict__ b2l,
    const float* __restrict__ w2r,
    const float* __restrict__ wfc, const float* __restrict__ bfc,
    float* __restrict__ out) {
    __shared__ float wt[64 * 128];   // 32 KB K-chunk weight tile (reused for wfc)
    __shared__ float inA[16 * 128];  // scaled agg2 rows; reused for normalized h2 rows
    __shared__ float inB[16 * 128];  // h1 rows
    const int t = threadIdx.x;
    const int jq = t & 31, ngq = t >> 5;
    const int base = blockIdx.x * 16;
    float4* wt4 = (float4*)wt;

    // stage inputs: 16 nodes x 128 feats, 2 float4 per thread per matrix
#pragma unroll
    for (int i = 0; i < 2; i++) {
        int idx = t + 256 * i;
        int node = idx >> 5, kq = idx & 31;
        float ic = inv[base + node];
        float4 a = ((const float4*)agg2)[(base + node) * 32 + kq];
        a.x *= ic; a.y *= ic; a.z *= ic; a.w *= ic;
        ((float4*)inA)[idx] = a;
        ((float4*)inB)[idx] = ((const float4*)h1)[(base + node) * 32 + kq];
    }
    const float4 bv = ((const float4*)b2l)[jq];
    float4 acc0 = bv, acc1 = bv;
    const int n0 = ngq * 2, n1 = ngq * 2 + 1;

#pragma unroll
    for (int pass = 0; pass < 4; pass++) {
        const float4* W4 = (const float4*)((pass < 2) ? w2l : w2r);
        const int kc = pass & 1;
        __syncthreads();  // previous tile readers done (also covers staging on pass 0)
#pragma unroll
        for (int i = 0; i < 8; i++) wt4[t + 256 * i] = W4[kc * 2048 + t + 256 * i];
        __syncthreads();
        const float* IN = (pass < 2) ? inA : inB;
        const int r0 = n0 * 128 + kc * 64, r1 = n1 * 128 + kc * 64;
#pragma unroll
        for (int k = 0; k < 64; k++) {
            float4 w4 = wt4[k * 32 + jq];
            float a0 = IN[r0 + k], a1 = IN[r1 + k];
            acc0.x += a0 * w4.x; acc0.y += a0 * w4.y; acc0.z += a0 * w4.z; acc0.w += a0 * w4.w;
            acc1.x += a1 * w4.x; acc1.y += a1 * w4.y; acc1.z += a1 * w4.z; acc1.w += a1 * w4.w;
        }
    }
    __syncthreads();  // all wt/in readers done

    // normalize rows, write h2 into inA
    {
        float ss = acc0.x * acc0.x + acc0.y * acc0.y + acc0.z * acc0.z + acc0.w * acc0.w;
        ss += __shfl_xor(ss, 1); ss += __shfl_xor(ss, 2); ss += __shfl_xor(ss, 4);
        ss += __shfl_xor(ss, 8); ss += __shfl_xor(ss, 16);
        float iv = 1.0f / fmaxf(sqrtf(ss), 1e-12f);
        float4 o; o.x = acc0.x * iv; o.y = acc0.y * iv; o.z = acc0.z * iv; o.w = acc0.w * iv;
        ((float4*)inA)[n0 * 32 + jq] = o;
    }
    {
        float ss = acc1.x * acc1.x + acc1.y * acc1.y + acc1.z * acc1.z + acc1.w * acc1.w;
        ss += __shfl_xor(ss, 1); ss += __shfl_xor(ss, 2); ss += __shfl_xor(ss, 4);
        ss += __shfl_xor(ss, 8); ss += __shfl_xor(ss, 16);
        float iv = 1.0f / fmaxf(sqrtf(ss), 1e-12f);
        float4 o; o.x = acc1.x * iv; o.y = acc1.y * iv; o.z = acc1.z * iv; o.w = acc1.w * iv;
        ((float4*)inA)[n1 * 32 + jq] = o;
    }
    // load wfc (128x16) into wt
#pragma unroll
    for (int i = 0; i < 8; i++) wt[t + 256 * i] = wfc[t + 256 * i];
    __syncthreads();
    // FC: 16 nodes x 16 outputs = 256 threads
    {
        int n = t >> 4, o = t & 15;
        float s = bfc[o];
#pragma unroll
        for (int k = 0; k < 128; k++) s += inA[n * 128 + k] * wt[k * 16 + o];
        out[(base + n) * 16 + o] = s;
    }
}

extern "C" void kernel_launch(void* const* d_in, const int* in_sizes, int n_in,
                              void* d_out, int out_size, void* d_ws, size_t ws_size,
                              hipStream_t stream) {
    const float* x     = (const float*)d_in[0];
    const int*   ei    = (const int*)d_in[1];
    const float* w1l   = (const float*)d_in[2];
    const float* b1l   = (const float*)d_in[3];
    const float* w1r   = (const float*)d_in[4];
    const float* gamma = (const float*)d_in[5];
    const float* beta  = (const float*)d_in[6];
    const float* w2l   = (const float*)d_in[7];
    const float* b2l   = (const float*)d_in[8];
    const float* w2r   = (const float*)d_in[9];
    const float* wfc   = (const float*)d_in[10];
    const float* bfc   = (const float*)d_in[11];
    float* out = (float*)d_out;

    float* W = (float*)d_ws;
    float* cnt   = W + OFS_CNT;
    float* agg1  = W + OFS_AGG1;
    float* agg2  = W + OFS_AGG2;
    float* h1    = W + OFS_H1;
    float* invc  = W + OFS_INV;
    float* stats = W + OFS_STATS;
    float* part  = W + OFS_PART;

    // zero cnt + agg1 + agg2 (contiguous 193*NN floats)
    hipMemsetAsync(W, 0, (size_t)193 * NN * sizeof(float), stream);

    k_scatter1<<<(NE * 64) / 256, 256, 0, stream>>>(x, ei, agg1, cnt);
    k_invcnt<<<(NN + 255) / 256, 256, 0, stream>>>(cnt, invc);
    k_gemm1<<<PART_BLOCKS, 256, 0, stream>>>(agg1, x, invc, w1l, b1l, w1r, h1, part);
    k_bnfin<<<1, 128, 0, stream>>>(part, gamma, beta, stats);
    k_bnapply<<<(NN * 32) / 256, 256, 0, stream>>>(h1, stats);
    k_scatter2<<<(NE * 128) / 256, 256, 0, stream>>>(h1, ei, agg2);
    k_gemm2<<<NN / 16, 256, 0, stream>>>(agg2, h1, invc, w2l, b2l, w2r, wfc, bfc, out);
}

// Round 2
// 746.778 us; speedup vs baseline: 1.9596x; 1.9596x over previous
//
#include <hip/hip_runtime.h>
#include <math.h>

#define NN 100000
#define NE 1600000
#define NB1 391          // ceil(NN/256) scan blocks
#define PART_BLOCKS 512

// ws layout in 4-byte units
#define OFS_DEG   0
#define OFS_CUR   (NN)
#define OFS_RP    (2*NN)
#define OFS_BSUM  (3*NN)
#define OFS_BSCAN (3*NN + 512)
#define OFS_CSR   (3*NN + 1024)
#define OFS_INV   (3*NN + 1024 + NE)
#define OFS_HAS   (OFS_INV + NN)
#define OFS_H1    (OFS_HAS + NN)
#define OFS_AGG2  (OFS_H1 + 128*NN)
#define OFS_AGG1  (OFS_AGG2)            /* alias: agg1 consumed before agg2 written */
#define OFS_STATS (OFS_AGG2 + 128*NN)
#define OFS_PART  (OFS_STATS + 256)

// ---------------- CSR build ----------------
__global__ void k_hist(const int* __restrict__ ei, int* __restrict__ deg) {
    int e = blockIdx.x * 256 + threadIdx.x;
    if (e < NE) atomicAdd(&deg[ei[NE + e]], 1);
}

__global__ void k_scan1(const int* __restrict__ deg, int* __restrict__ bsum) {
    __shared__ int sb[256];
    int i = blockIdx.x * 256 + threadIdx.x;
    sb[threadIdx.x] = (i < NN) ? deg[i] : 0;
    __syncthreads();
    for (int off = 128; off > 0; off >>= 1) {
        if (threadIdx.x < off) sb[threadIdx.x] += sb[threadIdx.x + off];
        __syncthreads();
    }
    if (threadIdx.x == 0) bsum[blockIdx.x] = sb[0];
}

__global__ void k_scan2(const int* __restrict__ bsum, int* __restrict__ bscan) {
    __shared__ int sb[512];
    int t = threadIdx.x;
    int v = (t < NB1) ? bsum[t] : 0;
    sb[t] = v;
    __syncthreads();
    for (int off = 1; off < 512; off <<= 1) {
        int u = (t >= off) ? sb[t - off] : 0;
        __syncthreads();
        sb[t] += u;
        __syncthreads();
    }
    if (t < NB1) bscan[t] = sb[t] - v;   // exclusive
}

__global__ void k_scan3(const int* __restrict__ deg, const int* __restrict__ bscan,
                        int* __restrict__ rp, int* __restrict__ cur,
                        float* __restrict__ inv, float* __restrict__ has) {
    __shared__ int sb[256];
    int t = threadIdx.x;
    int i = blockIdx.x * 256 + t;
    int d = (i < NN) ? deg[i] : 0;
    sb[t] = d;
    __syncthreads();
    for (int off = 1; off < 256; off <<= 1) {
        int u = (t >= off) ? sb[t - off] : 0;
        __syncthreads();
        sb[t] += u;
        __syncthreads();
    }
    if (i < NN) {
        int start = sb[t] - d + bscan[blockIdx.x];  // exclusive prefix
        rp[i] = start;
        cur[i] = start;
        inv[i] = 1.0f / fmaxf((float)d, 1.0f);
        has[i] = (d > 0) ? 1.0f : 0.0f;
    }
}

__global__ void k_fill(const int* __restrict__ ei, int* __restrict__ cur,
                       int* __restrict__ csr) {
    int e = blockIdx.x * 256 + threadIdx.x;
    if (e < NE) {
        int d = ei[NE + e];
        int pos = atomicAdd(&cur[d], 1);
        csr[pos] = ei[e];
    }
}

// ---------------- gather-aggregate layer 1: agg1[n] = mean_{s in N(n)} x[s]  ----------------
__global__ __launch_bounds__(256) void k_agg1(
    const float* __restrict__ x, const int* __restrict__ csr,
    const int* __restrict__ rp, const int* __restrict__ deg,
    const float* __restrict__ inv, float* __restrict__ agg1) {
    int t = threadIdx.x;
    int lane = t & 63;
    int node = blockIdx.x * 4 + (t >> 6);
    int len = deg[node];
    const int* cp = csr + rp[node];
    float a0 = 0.f, a1 = 0.f;
    int j = 0;
    for (; j + 1 < len; j += 2) {
        int s0 = cp[j], s1 = cp[j + 1];
        a0 += x[s0 * 64 + lane];
        a1 += x[s1 * 64 + lane];
    }
    if (j < len) a0 += x[cp[j] * 64 + lane];
    agg1[node * 64 + lane] = (a0 + a1) * inv[node];
}

// ---------------- gather-aggregate layer 2: agg2[n] = mean_{s in N(n)} h1[s] ----------------
__global__ __launch_bounds__(256) void k_agg2(
    const float* __restrict__ h1, const int* __restrict__ csr,
    const int* __restrict__ rp, const int* __restrict__ deg,
    const float* __restrict__ inv, float* __restrict__ agg2) {
    int t = threadIdx.x;
    int lane = t & 63;
    int node = blockIdx.x * 4 + (t >> 6);
    int len = deg[node];
    const int* cp = csr + rp[node];
    const float2* h2 = (const float2*)h1;
    float2 a0 = {0.f, 0.f}, a1 = {0.f, 0.f};
    int j = 0;
    for (; j + 1 < len; j += 2) {
        int s0 = cp[j], s1 = cp[j + 1];
        float2 v0 = h2[s0 * 64 + lane];
        float2 v1 = h2[s1 * 64 + lane];
        a0.x += v0.x; a0.y += v0.y;
        a1.x += v1.x; a1.y += v1.y;
    }
    if (j < len) {
        float2 v = h2[cp[j] * 64 + lane];
        a0.x += v.x; a0.y += v.y;
    }
    float ic = inv[node];
    float2 r; r.x = (a0.x + a1.x) * ic; r.y = (a0.y + a1.y) * ic;
    ((float2*)agg2)[node * 64 + lane] = r;
}

// ---------------- layer 1: out = agg1 @ w1l + b1l + x @ w1r ; L2norm ; relu ; BN col stats ----------------
__global__ __launch_bounds__(256) void k_gemm1(
    const float* __restrict__ agg1, const float* __restrict__ x,
    const float* __restrict__ w1l, const float* __restrict__ b1l,
    const float* __restrict__ w1r,
    float* __restrict__ h1, float* __restrict__ part) {
    __shared__ float wt[64 * 128];   // 32 KB weight tile
    __shared__ float inA[16 * 64];   // mean-agg rows
    __shared__ float inB[16 * 64];   // x rows
    __shared__ float cs[128];
    __shared__ float cq[128];
    const int t = threadIdx.x;
    const int jq = t & 31;   // 4 cols: jq*4..jq*4+3
    const int ngq = t >> 5;  // 2 nodes
    if (t < 128) { cs[t] = 0.f; cq[t] = 0.f; }
    float ls0 = 0, ls1 = 0, ls2 = 0, ls3 = 0;
    float lq0 = 0, lq1 = 0, lq2 = 0, lq3 = 0;
    const float4* w1l4 = (const float4*)w1l;
    const float4* w1r4 = (const float4*)w1r;
    float4* wt4 = (float4*)wt;
    const float4 bv = ((const float4*)b1l)[jq];

    for (int g = blockIdx.x; g < NN / 16; g += gridDim.x) {
        const int base = g * 16;
        {   // stage 16 nodes x 64 feats (1 float4 per thread each)
            int node = t >> 4, kq = t & 15;
            ((float4*)inA)[t] = ((const float4*)agg1)[(base + node) * 16 + kq];
            ((float4*)inB)[t] = ((const float4*)x)[(base + node) * 16 + kq];
        }
#pragma unroll
        for (int i = 0; i < 8; i++) wt4[t + 256 * i] = w1l4[t + 256 * i];
        __syncthreads();

        float4 acc0 = bv, acc1 = bv;
        const int r0 = (ngq * 2) * 64, r1 = (ngq * 2 + 1) * 64;
#pragma unroll
        for (int k = 0; k < 64; k++) {
            float4 w4 = wt4[k * 32 + jq];
            float a0 = inA[r0 + k], a1 = inA[r1 + k];
            acc0.x += a0 * w4.x; acc0.y += a0 * w4.y; acc0.z += a0 * w4.z; acc0.w += a0 * w4.w;
            acc1.x += a1 * w4.x; acc1.y += a1 * w4.y; acc1.z += a1 * w4.z; acc1.w += a1 * w4.w;
        }
        __syncthreads();
#pragma unroll
        for (int i = 0; i < 8; i++) wt4[t + 256 * i] = w1r4[t + 256 * i];
        __syncthreads();
#pragma unroll
        for (int k = 0; k < 64; k++) {
            float4 w4 = wt4[k * 32 + jq];
            float a0 = inB[r0 + k], a1 = inB[r1 + k];
            acc0.x += a0 * w4.x; acc0.y += a0 * w4.y; acc0.z += a0 * w4.z; acc0.w += a0 * w4.w;
            acc1.x += a1 * w4.x; acc1.y += a1 * w4.y; acc1.z += a1 * w4.z; acc1.w += a1 * w4.w;
        }
        // epilogue node 0
        {
            float ss = acc0.x * acc0.x + acc0.y * acc0.y + acc0.z * acc0.z + acc0.w * acc0.w;
            ss += __shfl_xor(ss, 1); ss += __shfl_xor(ss, 2); ss += __shfl_xor(ss, 4);
            ss += __shfl_xor(ss, 8); ss += __shfl_xor(ss, 16);
            float iv = 1.0f / fmaxf(sqrtf(ss), 1e-12f);
            float v0 = fmaxf(acc0.x * iv, 0.f), v1 = fmaxf(acc0.y * iv, 0.f);
            float v2 = fmaxf(acc0.z * iv, 0.f), v3 = fmaxf(acc0.w * iv, 0.f);
            float4 o; o.x = v0; o.y = v1; o.z = v2; o.w = v3;
            ((float4*)&h1[(base + ngq * 2) * 128])[jq] = o;
            ls0 += v0; ls1 += v1; ls2 += v2; ls3 += v3;
            lq0 += v0 * v0; lq1 += v1 * v1; lq2 += v2 * v2; lq3 += v3 * v3;
        }
        // epilogue node 1
        {
            float ss = acc1.x * acc1.x + acc1.y * acc1.y + acc1.z * acc1.z + acc1.w * acc1.w;
            ss += __shfl_xor(ss, 1); ss += __shfl_xor(ss, 2); ss += __shfl_xor(ss, 4);
            ss += __shfl_xor(ss, 8); ss += __shfl_xor(ss, 16);
            float iv = 1.0f / fmaxf(sqrtf(ss), 1e-12f);
            float v0 = fmaxf(acc1.x * iv, 0.f), v1 = fmaxf(acc1.y * iv, 0.f);
            float v2 = fmaxf(acc1.z * iv, 0.f), v3 = fmaxf(acc1.w * iv, 0.f);
            float4 o; o.x = v0; o.y = v1; o.z = v2; o.w = v3;
            ((float4*)&h1[(base + ngq * 2 + 1) * 128])[jq] = o;
            ls0 += v0; ls1 += v1; ls2 += v2; ls3 += v3;
            lq0 += v0 * v0; lq1 += v1 * v1; lq2 += v2 * v2; lq3 += v3 * v3;
        }
        __syncthreads();  // before next staging overwrites LDS
    }
    // flush per-block BN partial stats
    __syncthreads();
    atomicAdd(&cs[jq * 4 + 0], ls0); atomicAdd(&cs[jq * 4 + 1], ls1);
    atomicAdd(&cs[jq * 4 + 2], ls2); atomicAdd(&cs[jq * 4 + 3], ls3);
    atomicAdd(&cq[jq * 4 + 0], lq0); atomicAdd(&cq[jq * 4 + 1], lq1);
    atomicAdd(&cq[jq * 4 + 2], lq2); atomicAdd(&cq[jq * 4 + 3], lq3);
    __syncthreads();
    if (t < 128) {
        part[blockIdx.x * 256 + t] = cs[t];
        part[blockIdx.x * 256 + 128 + t] = cq[t];
    }
}

// ---------------- BN finalize: scale/shift from partials ----------------
__global__ void k_bnfin(const float* __restrict__ part, const float* __restrict__ gamma,
                        const float* __restrict__ beta, float* __restrict__ stats) {
    int t = threadIdx.x;  // 128
    float s = 0.f, q = 0.f;
    for (int b = 0; b < PART_BLOCKS; b++) {
        s += part[b * 256 + t];
        q += part[b * 256 + 128 + t];
    }
    float mean = s / (float)NN;
    float var = q / (float)NN - mean * mean;
    float sc = gamma[t] * rsqrtf(var + 1e-5f);
    stats[t] = sc;
    stats[128 + t] = beta[t] - mean * sc;
}

// ---------------- layer 2 + L2norm + FC, fused (BN folded into staging) ----------------
__global__ __launch_bounds__(256) void k_gemm2(
    const float* __restrict__ agg2, const float* __restrict__ h1,
    const float* __restrict__ has, const float* __restrict__ stats,
    const float* __restrict__ w2l, const float* __restrict__ b2l,
    const float* __restrict__ w2r,
    const float* __restrict__ wfc, const float* __restrict__ bfc,
    float* __restrict__ out) {
    __shared__ float wt[64 * 128];   // 32 KB K-chunk weight tile (reused for wfc)
    __shared__ float inA[16 * 128];  // BN'd mean-agg rows; reused for normalized h2 rows
    __shared__ float inB[16 * 128];  // BN'd h1 rows
    const int t = threadIdx.x;
    const int jq = t & 31, ngq = t >> 5;
    const int base = blockIdx.x * 16;
    float4* wt4 = (float4*)wt;
    const float4* stats4 = (const float4*)stats;

    // stage inputs: 16 nodes x 128 feats, 2 float4 per thread per matrix; BN applied here
#pragma unroll
    for (int i = 0; i < 2; i++) {
        int idx = t + 256 * i;
        int node = idx >> 5, kq = idx & 31;
        float4 sc = stats4[kq];
        float4 sh = stats4[32 + kq];
        float hv = has[base + node];
        float4 a = ((const float4*)agg2)[(base + node) * 32 + kq];
        a.x = a.x * sc.x + sh.x * hv; a.y = a.y * sc.y + sh.y * hv;
        a.z = a.z * sc.z + sh.z * hv; a.w = a.w * sc.w + sh.w * hv;
        ((float4*)inA)[idx] = a;
        float4 b = ((const float4*)h1)[(base + node) * 32 + kq];
        b.x = b.x * sc.x + sh.x; b.y = b.y * sc.y + sh.y;
        b.z = b.z * sc.z + sh.z; b.w = b.w * sc.w + sh.w;
        ((float4*)inB)[idx] = b;
    }
    const float4 bv = ((const float4*)b2l)[jq];
    float4 acc0 = bv, acc1 = bv;
    const int n0 = ngq * 2, n1 = ngq * 2 + 1;

#pragma unroll
    for (int pass = 0; pass < 4; pass++) {
        const float4* W4 = (const float4*)((pass < 2) ? w2l : w2r);
        const int kc = pass & 1;
        __syncthreads();  // previous tile readers done (also covers staging on pass 0)
#pragma unroll
        for (int i = 0; i < 8; i++) wt4[t + 256 * i] = W4[kc * 2048 + t + 256 * i];
        __syncthreads();
        const float* IN = (pass < 2) ? inA : inB;
        const int r0 = n0 * 128 + kc * 64, r1 = n1 * 128 + kc * 64;
#pragma unroll
        for (int k = 0; k < 64; k++) {
            float4 w4 = wt4[k * 32 + jq];
            float a0 = IN[r0 + k], a1 = IN[r1 + k];
            acc0.x += a0 * w4.x; acc0.y += a0 * w4.y; acc0.z += a0 * w4.z; acc0.w += a0 * w4.w;
            acc1.x += a1 * w4.x; acc1.y += a1 * w4.y; acc1.z += a1 * w4.z; acc1.w += a1 * w4.w;
        }
    }
    __syncthreads();  // all wt/in readers done

    // normalize rows, write h2 into inA
    {
        float ss = acc0.x * acc0.x + acc0.y * acc0.y + acc0.z * acc0.z + acc0.w * acc0.w;
        ss += __shfl_xor(ss, 1); ss += __shfl_xor(ss, 2); ss += __shfl_xor(ss, 4);
        ss += __shfl_xor(ss, 8); ss += __shfl_xor(ss, 16);
        float iv = 1.0f / fmaxf(sqrtf(ss), 1e-12f);
        float4 o; o.x = acc0.x * iv; o.y = acc0.y * iv; o.z = acc0.z * iv; o.w = acc0.w * iv;
        ((float4*)inA)[n0 * 32 + jq] = o;
    }
    {
        float ss = acc1.x * acc1.x + acc1.y * acc1.y + acc1.z * acc1.z + acc1.w * acc1.w;
        ss += __shfl_xor(ss, 1); ss += __shfl_xor(ss, 2); ss += __shfl_xor(ss, 4);
        ss += __shfl_xor(ss, 8); ss += __shfl_xor(ss, 16);
        float iv = 1.0f / fmaxf(sqrtf(ss), 1e-12f);
        float4 o; o.x = acc1.x * iv; o.y = acc1.y * iv; o.z = acc1.z * iv; o.w = acc1.w * iv;
        ((float4*)inA)[n1 * 32 + jq] = o;
    }
    // load wfc (128x16) into wt
#pragma unroll
    for (int i = 0; i < 8; i++) wt[t + 256 * i] = wfc[t + 256 * i];
    __syncthreads();
    // FC: 16 nodes x 16 outputs = 256 threads
    {
        int n = t >> 4, o = t & 15;
        float s = bfc[o];
#pragma unroll
        for (int k = 0; k < 128; k++) s += inA[n * 128 + k] * wt[k * 16 + o];
        out[(base + n) * 16 + o] = s;
    }
}

extern "C" void kernel_launch(void* const* d_in, const int* in_sizes, int n_in,
                              void* d_out, int out_size, void* d_ws, size_t ws_size,
                              hipStream_t stream) {
    const float* x     = (const float*)d_in[0];
    const int*   ei    = (const int*)d_in[1];
    const float* w1l   = (const float*)d_in[2];
    const float* b1l   = (const float*)d_in[3];
    const float* w1r   = (const float*)d_in[4];
    const float* gamma = (const float*)d_in[5];
    const float* beta  = (const float*)d_in[6];
    const float* w2l   = (const float*)d_in[7];
    const float* b2l   = (const float*)d_in[8];
    const float* w2r   = (const float*)d_in[9];
    const float* wfc   = (const float*)d_in[10];
    const float* bfc   = (const float*)d_in[11];
    float* out = (float*)d_out;

    float* W = (float*)d_ws;
    int* deg   = (int*)(W + OFS_DEG);
    int* cur   = (int*)(W + OFS_CUR);
    int* rp    = (int*)(W + OFS_RP);
    int* bsum  = (int*)(W + OFS_BSUM);
    int* bscan = (int*)(W + OFS_BSCAN);
    int* csr   = (int*)(W + OFS_CSR);
    float* inv   = W + OFS_INV;
    float* has   = W + OFS_HAS;
    float* h1    = W + OFS_H1;
    float* agg1  = W + OFS_AGG1;
    float* agg2  = W + OFS_AGG2;
    float* stats = W + OFS_STATS;
    float* part  = W + OFS_PART;

    // zero degree histogram only
    hipMemsetAsync(deg, 0, NN * sizeof(int), stream);

    k_hist <<<(NE + 255) / 256, 256, 0, stream>>>(ei, deg);
    k_scan1<<<NB1, 256, 0, stream>>>(deg, bsum);
    k_scan2<<<1, 512, 0, stream>>>(bsum, bscan);
    k_scan3<<<NB1, 256, 0, stream>>>(deg, bscan, rp, cur, inv, has);
    k_fill <<<(NE + 255) / 256, 256, 0, stream>>>(ei, cur, csr);

    k_agg1 <<<NN / 4, 256, 0, stream>>>(x, csr, rp, deg, inv, agg1);
    k_gemm1<<<PART_BLOCKS, 256, 0, stream>>>(agg1, x, w1l, b1l, w1r, h1, part);
    k_bnfin<<<1, 128, 0, stream>>>(part, gamma, beta, stats);
    k_agg2 <<<NN / 4, 256, 0, stream>>>(h1, csr, rp, deg, inv, agg2);
    k_gemm2<<<NN / 16, 256, 0, stream>>>(agg2, h1, has, stats, w2l, b2l, w2r, wfc, bfc, out);
}